// Round 6
// baseline (617.421 us; speedup 1.0000x reference)
//
#include <hip/hip_runtime.h>
#include <math.h>

#define DIM     2048
#define NEXP    64
#define CAP     128
#define NTOK    8192
#define NTILE   256            // 256 tiles of 32 tokens
#define KC      256            // K-chunk staged in LDS
#define NCH     (DIM/KC)       // 8 chunks
#define XWSTR   260            // row stride for xs/ws tiles (KC+4)
#define PSTR    68             // row stride for partial/logit tiles
#define RF      67108864       // floats per output region (S*E*C)

typedef float vfloat4 __attribute__((ext_vector_type(4)));

// ---------------- 1. gate GEMM + softmax + argmax + within-tile rank --------
// 256 blocks x 512 thr (8 waves/CU, 2/SIMD -- R5 ran 4 waves/CU and left all
// LDS/VMEM latency exposed). Tile 32 tok x 64 exp, K sliced 16-way.
// Thread (sl = tid>>5, tg = tid&3, eg = (tid&31)>>2) owns tokens tg+4j,
// experts eg+8m (j,m in 0..7) over kk in [sl*16,(sl+1)*16) of each chunk.
__global__ __launch_bounds__(512, 2) void gate_kernel(
    const float* __restrict__ x, const float* __restrict__ wg,
    int* __restrict__ expert_idx, float* __restrict__ gate_top,
    int* __restrict__ rank,
    float* __restrict__ me_partial, int* __restrict__ counts)
{
    __shared__ __align__(16) float smem[(32 + NEXP) * XWSTR]; // 99,840 B
    __shared__ float me_w[8 * NEXP];
    __shared__ int   cnt_w[8 * NEXP];
    __shared__ int   exp_s[32];

    float* xs = smem;                 // [32][XWSTR]
    float* ws = smem + 32 * XWSTR;    // [64][XWSTR]

    const int tid  = threadIdx.x;
    const int gb   = blockIdx.x;
    const int tok0 = gb * 32;
    const int sl   = tid >> 5;        // k-slice 0..15
    const int i    = tid & 31;
    const int tg   = i & 3;           // token group
    const int eg   = i >> 2;          // expert group 0..7
    const int kb   = sl * 16;         // slice's kk base within chunk

    float acc[8][8] = {};

    for (int ch = 0; ch < NCH; ++ch) {
        const int k0 = ch * KC;
        // stage x tile [32][KC]: 2048 f4, 4 per thread, coalesced rows
        #pragma unroll
        for (int q = 0; q < 4; ++q) {
            int id = tid + (q << 9);
            int r = id >> 6, c = id & 63;
            float4 v = *(const float4*)(x + (size_t)(tok0 + r) * DIM + k0 + 4 * c);
            *(float4*)(&xs[r * XWSTR + 4 * c]) = v;
        }
        // stage w tile [64][KC]: 4096 f4, 8 per thread
        #pragma unroll
        for (int q = 0; q < 8; ++q) {
            int id = tid + (q << 9);
            int r = id >> 6, c = id & 63;
            float4 v = *(const float4*)(wg + (size_t)r * DIM + k0 + 4 * c);
            *(float4*)(&ws[r * XWSTR + 4 * c]) = v;
        }
        __syncthreads();

        #pragma unroll
        for (int q2 = 0; q2 < 4; ++q2) {        // 4-kk steps, 16 kk per slice
            const int kk = kb + 4 * q2;
            float4 xt[8], we[8];
            #pragma unroll
            for (int j = 0; j < 8; ++j)
                xt[j] = *(const float4*)(&xs[(tg + 4 * j) * XWSTR + kk]);
            #pragma unroll
            for (int m = 0; m < 8; ++m)
                we[m] = *(const float4*)(&ws[(eg + 8 * m) * XWSTR + kk]);
            #pragma unroll
            for (int j = 0; j < 8; ++j)
                #pragma unroll
                for (int m = 0; m < 8; ++m) {
                    acc[j][m] = fmaf(xt[j].x, we[m].x, acc[j][m]);
                    acc[j][m] = fmaf(xt[j].y, we[m].y, acc[j][m]);
                    acc[j][m] = fmaf(xt[j].z, we[m].z, acc[j][m]);
                    acc[j][m] = fmaf(xt[j].w, we[m].w, acc[j][m]);
                }
        }
        __syncthreads();
    }

    // ---- reduce 16 k-slices: upper 8 deposit, lower 8 add, then tree ----
    float* part = smem;                 // [8][32][PSTR] = 17408 floats
    float* lgt  = smem + 8 * 32 * PSTR; // [32][PSTR]
    if (sl >= 8) {
        #pragma unroll
        for (int j = 0; j < 8; ++j)
            #pragma unroll
            for (int m = 0; m < 8; ++m)
                part[((sl - 8) * 32 + tg + 4 * j) * PSTR + eg + 8 * m] = acc[j][m];
    }
    __syncthreads();
    if (sl < 8) {
        // read+accumulate+write-back: each element touched by exactly this thread
        #pragma unroll
        for (int j = 0; j < 8; ++j)
            #pragma unroll
            for (int m = 0; m < 8; ++m) {
                int idx = ((sl) * 32 + tg + 4 * j) * PSTR + eg + 8 * m;
                part[idx] += acc[j][m];
            }
    }
    __syncthreads();

    {   // final 8-slice reduction: 512 thr, thread -> (row t, 4 experts)
        int t  = tid >> 4;
        int e0 = (tid & 15) << 2;
        float4 a = {0, 0, 0, 0};
        #pragma unroll
        for (int s2 = 0; s2 < 8; ++s2) {
            float4 p = *(const float4*)(&part[(s2 * 32 + t) * PSTR + e0]);
            a.x += p.x; a.y += p.y; a.z += p.z; a.w += p.w;
        }
        *(float4*)(&lgt[t * PSTR + e0]) = a;   // lgt disjoint from part
    }
    __syncthreads();

    // ---- softmax + argmax: 8 waves x 4 rows, lane = expert ----
    const int lane = tid & 63;
    const int wv   = tid >> 6;
    float me_acc  = 0.0f;
    int   cnt_acc = 0;
    #pragma unroll
    for (int r4 = 0; r4 < 4; ++r4) {
        int row = wv * 4 + r4;
        float v = lgt[row * PSTR + lane];
        float m = v; int mi = lane;
        #pragma unroll
        for (int off = 32; off > 0; off >>= 1) {
            float om  = __shfl_xor(m, off);
            int   omi = __shfl_xor(mi, off);
            if (om > m || (om == m && omi < mi)) { m = om; mi = omi; }
        }
        float ex = __expf(v - m);
        float sm = ex;
        #pragma unroll
        for (int off = 32; off > 0; off >>= 1) sm += __shfl_xor(sm, off);
        me_acc += ex / sm;
        if (lane == mi) {
            expert_idx[tok0 + row] = mi;
            gate_top[tok0 + row]   = 1.0f / sm;
            exp_s[row] = mi;
            ++cnt_acc;
        }
    }
    me_w[wv * NEXP + lane]  = me_acc;
    cnt_w[wv * NEXP + lane] = cnt_acc;
    __syncthreads();

    if (tid < 32) {  // within-tile rank (token order), <=31 LDS compares
        int e = exp_s[tid];
        int rk = 0;
        for (int u = 0; u < tid; ++u) rk += (exp_s[u] == e) ? 1 : 0;
        rank[tok0 + tid] = rk;
    }
    if (tid < NEXP) {
        float ms = 0.f; int cs = 0;
        #pragma unroll
        for (int w = 0; w < 8; ++w) { ms += me_w[w * NEXP + tid]; cs += cnt_w[w * NEXP + tid]; }
        me_partial[gb * NEXP + tid] = ms;
        counts[gb * NEXP + tid]     = cs;
    }
}

// ---------------- 2. prefix over 256 tiles + l_aux + per-token hot ----------
// 1 block x 1024 thr. Scan kept in LDS (bo_l) -- no global visibility hazard.
// hot[s] = e*128 + loc if kept, -1 if capacity-dropped.
__global__ __launch_bounds__(1024) void prefix_laux(
    const float* __restrict__ me_partial, const int* __restrict__ counts,
    const int* __restrict__ expert_idx, const int* __restrict__ rank,
    int* __restrict__ hot, float* __restrict__ out)
{
    __shared__ int   bo_l[NTILE * NEXP];   // 64 KB: exclusive offsets
    __shared__ int   cnt_l[16 * NEXP];
    __shared__ float me_l[16 * NEXP];
    __shared__ int   cnt_tot[NEXP];
    __shared__ float me_tot[NEXP];

    const int tid = threadIdx.x;
    const int e   = tid & 63;
    const int g   = tid >> 6;          // 0..15

    int cs = 0; float ms = 0.f;
    #pragma unroll
    for (int i = 0; i < 16; ++i) {
        int t = g * 16 + i;
        cs += counts[t * NEXP + e];
        ms += me_partial[t * NEXP + e];
    }
    cnt_l[g * NEXP + e] = cs;
    me_l[g * NEXP + e]  = ms;
    __syncthreads();

    if (g == 0) {                      // serial scan of 16 group-sums
        int run = 0; float mt = 0.f;
        #pragma unroll
        for (int i = 0; i < 16; ++i) {
            int c = cnt_l[i * NEXP + e];
            cnt_l[i * NEXP + e] = run;
            run += c;
            mt  += me_l[i * NEXP + e];
        }
        cnt_tot[e] = run;
        me_tot[e]  = mt;
    }
    __syncthreads();

    int run = cnt_l[g * NEXP + e];
    #pragma unroll
    for (int i = 0; i < 16; ++i) {
        int t = g * 16 + i;
        bo_l[t * NEXP + e] = run;
        run += counts[t * NEXP + e];   // L2-hot second read
    }
    __syncthreads();

    if (tid < NEXP) {
        float v = (me_tot[e] / (float)NTOK) * ((float)cnt_tot[e] / (float)NTOK);
        #pragma unroll
        for (int off = 32; off > 0; off >>= 1) v += __shfl_xor(v, off);
        if (e == 0) out[0] = v * (float)NEXP;   // mean(me*ce)*E*E == sum*E
    }

    #pragma unroll
    for (int ii = 0; ii < 8; ++ii) {           // per-token hot index
        int s  = tid + (ii << 10);
        int ex = expert_idx[s];
        int loc = bo_l[(s >> 5) * NEXP + ex] + rank[s];
        hot[s] = (loc < CAP) ? (ex * CAP + loc) : -1;
    }
}

// ---------------- 3. emit: write ALL 537 MB, value-or-zero ----------------
// Replaces fill_out + scatter_k: every output float written exactly once with
// plain (non-NT) coalesced float4 stores. 4096 blocks x 256 thr: blocks
// [0,2048) combine, [2048,4096) dispatch; block covers 8192 f4 = ~4 tokens.
__global__ __launch_bounds__(256) void emit_out(
    const int* __restrict__ hot, const float* __restrict__ pay,
    float* __restrict__ out)
{
    __shared__ int   hot_l[5];
    __shared__ float pay_l[5];

    const int tid = threadIdx.x;
    const int b   = blockIdx.x;
    const int reg = b >> 11;           // 0 combine, 1 dispatch
    const int zb  = b & 2047;
    const int s0  = zb * 4;            // first token this block touches

    if (tid < 5) {
        int s = s0 + tid;
        bool ok = (s < NTOK);
        hot_l[tid] = ok ? hot[s] : -1;
        pay_l[tid] = ok ? ((reg == 0) ? pay[s] : 1.0f) : 0.0f;
    }
    __syncthreads();

    // aligned f4 span of region: abs floats [reg*RF + 4, reg*RF + 4 + 4*16777215)
    float* base = out + (size_t)reg * RF + 4;
    #pragma unroll 8
    for (int q = 0; q < 32; ++q) {
        int i4 = zb * 8192 + tid + (q << 8);
        if (i4 < 16777215) {
            int r0 = 4 * i4 + 3;       // region-relative float offset of comp 0
            vfloat4 v;
            #pragma unroll
            for (int k = 0; k < 4; ++k) {
                int r  = r0 + k;
                int sl = (r >> 13) - s0;
                int w  = r & 8191;     // position within token row: e*128+c
                v[k] = (w == hot_l[sl]) ? pay_l[sl] : 0.0f;
            }
            *(vfloat4*)(base + (size_t)4 * i4) = v;
        }
    }
    // head floats (rel 0,1,2 = token 0) and tail float (rel RF-1 = token 8191)
    if (zb == 0 && tid < 3)
        out[(size_t)reg * RF + 1 + tid] = (tid == hot_l[0]) ? pay_l[0] : 0.0f;
    if (zb == 2047 && tid == 0)
        out[(size_t)reg * RF + RF] = (8191 == hot_l[3]) ? pay_l[3] : 0.0f;
}

extern "C" void kernel_launch(void* const* d_in, const int* in_sizes, int n_in,
                              void* d_out, int out_size, void* d_ws, size_t ws_size,
                              hipStream_t stream)
{
    const float* x  = (const float*)d_in[0];
    const float* wg = (const float*)d_in[1];
    float* out = (float*)d_out;

    char* ws = (char*)d_ws;
    int*   expert_idx = (int*)  (ws);             // 8192*4  = 32 KB
    float* gate_top   = (float*)(ws + 32768);     // 32 KB
    int*   rank       = (int*)  (ws + 65536);     // 32 KB
    float* me_partial = (float*)(ws + 98304);     // 64 KB
    int*   counts     = (int*)  (ws + 163840);    // 64 KB
    int*   hot        = (int*)  (ws + 229376);    // 32 KB   (total 256 KB)

    gate_kernel<<<NTILE, 512, 0, stream>>>(x, wg, expert_idx, gate_top, rank,
                                           me_partial, counts);
    prefix_laux<<<1, 1024, 0, stream>>>(me_partial, counts, expert_idx, rank,
                                        hot, out);
    emit_out<<<4096, 256, 0, stream>>>(hot, gate_top, out);
}